// Round 2
// baseline (132.578 us; speedup 1.0000x reference)
//
#include <hip/hip_runtime.h>
#include <hip/hip_bf16.h>
#include <math.h>

#define NQ 12
#define NS 4096          // 2^12 amplitudes
#define TPB 256
#define HALF (NS / 2)
#define PT (NS / TPB)    // 16 amplitudes per thread in full passes

// One block = one batch sample. State vector lives in LDS as float2 (re, im).
// Qubit q <-> bit position (NQ-1-q) of the flat state index (wire 0 = MSB).
//
// Dtype: reference declares float32; on-device detection via lam (== ones):
// first 4 bytes are 0x3F800000 if f32, 0x3F803F80 if the dataset was
// converted to bf16. Output dtype follows input dtype.
//
// Algebraic reductions vs reference:
//  - layer-0 RX on |0..0> done as direct product-state init
//  - each 12-CNOT ring collapsed to ONE basis permutation (prefix-XOR over
//    qubit-ordered bits + parity bit for qubit 0), applied via registers
//    (no second LDS buffer -> 32 KB LDS -> 2x occupancy)
//  - RY then RZ fused into a single complex 2x2 gate
//  - final layer's RZ dropped (diagonal phase, invisible to Z-measurement)

__device__ __forceinline__ float ldin(const void* p, int i, bool bf) {
    return bf ? __bfloat162float(((const __hip_bfloat16*)p)[i])
              : ((const float*)p)[i];
}

__device__ __forceinline__ int ring_perm(int i) {
    // new_bit[q] = XOR(a_0..a_q) for q>=1 ; new_bit[0] = XOR(a_1..a_11)
    int y = i ^ (i >> 1); y ^= y >> 2; y ^= y >> 4; y ^= y >> 8;
    return (y & 0x7FF) | (((__popc(i) ^ (i >> 11)) & 1) << 11);
}

__global__ __launch_bounds__(TPB) void vqc_kernel(
    const void* __restrict__ xp,    // [B, 12]
    const void* __restrict__ thp,   // [2, 12, 2]
    const void* __restrict__ lmp,   // [2, 12]
    void* __restrict__ outp)        // [B, 12]
{
    __shared__ float2 A[NS];
    __shared__ float red[4 * NQ];

    const int b = blockIdx.x;
    const int t = threadIdx.x;
    const int lane = t & 63;
    const int wave = t >> 6;

    const bool bf = (*(const unsigned int*)lmp) == 0x3F803F80u;

    // ---------------- layer 0: RX product-state init into A ----------------
    // RX(a)|0> = cos(a/2)|0> - i sin(a/2)|1>  => amp(s) = prod * (-i)^popc(s)
    float pcv[NQ], psv[NQ];
#pragma unroll
    for (int q = 0; q < NQ; ++q) {
        float h = 0.5f * ldin(lmp, q, bf) * ldin(xp, b * NQ + q, bf);
        sincosf(h, &psv[q], &pcv[q]);
    }
    for (int i = t; i < NS; i += TPB) {
        float m = 1.0f;
#pragma unroll
        for (int q = 0; q < NQ; ++q)
            m *= ((i >> (NQ - 1 - q)) & 1) ? psv[q] : pcv[q];
        int k = __popc(i) & 3;
        float2 a;
        a.x = (k == 0) ? m : ((k == 2) ? -m : 0.0f);
        a.y = (k == 3) ? m : ((k == 1) ? -m : 0.0f);
        A[i] = a;
    }
    __syncthreads();

    // ---------------- layer 0: CNOT ring as one permutation (via regs) ------
    {
        float2 v[PT]; int dst[PT];
#pragma unroll
        for (int k = 0; k < PT; ++k) {
            int i = k * TPB + t;
            v[k] = A[i];
            dst[k] = ring_perm(i);
        }
        __syncthreads();
#pragma unroll
        for (int k = 0; k < PT; ++k) A[dst[k]] = v[k];
        __syncthreads();
    }

    // ---------------- layer 0: fused G = RZ * RY ----------------------------
    for (int q = 0; q < NQ; ++q) {
        float hy = 0.5f * ldin(thp, q * 2 + 0, bf);
        float hz = 0.5f * ldin(thp, q * 2 + 1, bf);
        float cy, sy, cz, sz;
        sincosf(hy, &sy, &cy);
        sincosf(hz, &sz, &cz);
        // e0 = cz - i sz, e1 = cz + i sz ; G = [[e0*cy, -e0*sy],[e1*sy, e1*cy]]
        float g00x =  cz * cy, g00y = -sz * cy;
        float g01x = -cz * sy, g01y =  sz * sy;
        float g10x =  cz * sy, g10y =  sz * sy;
        float g11x =  cz * cy, g11y =  sz * cy;
        const int pc = NQ - 1 - q;
        const int mlo = (1 << pc) - 1;
        for (int j = t; j < HALF; j += TPB) {
            int i0 = ((j & ~mlo) << 1) | (j & mlo);
            int i1 = i0 | (1 << pc);
            float2 a0 = A[i0], a1 = A[i1];
            float2 n0, n1;
            n0.x = g00x * a0.x - g00y * a0.y + g01x * a1.x - g01y * a1.y;
            n0.y = g00x * a0.y + g00y * a0.x + g01x * a1.y + g01y * a1.x;
            n1.x = g10x * a0.x - g10y * a0.y + g11x * a1.x - g11y * a1.y;
            n1.y = g10x * a0.y + g10y * a0.x + g11x * a1.y + g11y * a1.x;
            A[i0] = n0; A[i1] = n1;
        }
        __syncthreads();
    }

    // ---------------- layer 1: RX gates -------------------------------------
    // RX: n0 = c*a0 - i s*a1 ; n1 = -i s*a0 + c*a1
    for (int q = 0; q < NQ; ++q) {
        float h = 0.5f * ldin(lmp, NQ + q, bf) * ldin(xp, b * NQ + q, bf);
        float c, s;
        sincosf(h, &s, &c);
        const int pc = NQ - 1 - q;
        const int mlo = (1 << pc) - 1;
        for (int j = t; j < HALF; j += TPB) {
            int i0 = ((j & ~mlo) << 1) | (j & mlo);
            int i1 = i0 | (1 << pc);
            float2 a0 = A[i0], a1 = A[i1];
            float2 n0, n1;
            n0.x = c * a0.x + s * a1.y;
            n0.y = c * a0.y - s * a1.x;
            n1.x = c * a1.x + s * a0.y;
            n1.y = c * a1.y - s * a0.x;
            A[i0] = n0; A[i1] = n1;
        }
        __syncthreads();
    }

    // ---------------- layer 1: CNOT ring (via regs) --------------------------
    {
        float2 v[PT]; int dst[PT];
#pragma unroll
        for (int k = 0; k < PT; ++k) {
            int i = k * TPB + t;
            v[k] = A[i];
            dst[k] = ring_perm(i);
        }
        __syncthreads();
#pragma unroll
        for (int k = 0; k < PT; ++k) A[dst[k]] = v[k];
        __syncthreads();
    }

    // ---------------- layer 1: RY only (final RZ is phase-only, dropped) ----
    for (int q = 0; q < NQ; ++q) {
        float hy = 0.5f * ldin(thp, 24 + q * 2 + 0, bf);
        float cy, sy;
        sincosf(hy, &sy, &cy);
        const int pc = NQ - 1 - q;
        const int mlo = (1 << pc) - 1;
        for (int j = t; j < HALF; j += TPB) {
            int i0 = ((j & ~mlo) << 1) | (j & mlo);
            int i1 = i0 | (1 << pc);
            float2 a0 = A[i0], a1 = A[i1];
            float2 n0, n1;
            n0.x = cy * a0.x - sy * a1.x;
            n0.y = cy * a0.y - sy * a1.y;
            n1.x = sy * a0.x + cy * a1.x;
            n1.y = sy * a0.y + cy * a1.y;
            A[i0] = n0; A[i1] = n1;
        }
        __syncthreads();
    }

    // ---------------- measurement: <Z_q> = sum_s (+-) |amp|^2 ---------------
    // i = k*256 + t : bits 8..11 come from k (qubits 0..3, compile-time signs),
    // bits 0..7 come from t (qubits 4..11, sign fixed per thread -> use ptot).
    float ptot = 0.f, zb0 = 0.f, zb1 = 0.f, zb2 = 0.f, zb3 = 0.f;
#pragma unroll
    for (int k = 0; k < NS / TPB; ++k) {
        float2 a = A[k * TPB + t];
        float p = a.x * a.x + a.y * a.y;
        ptot += p;
        zb0 += ((k >> 3) & 1) ? -p : p;
        zb1 += ((k >> 2) & 1) ? -p : p;
        zb2 += ((k >> 1) & 1) ? -p : p;
        zb3 += ((k >> 0) & 1) ? -p : p;
    }
    float z[NQ];
    z[0] = zb0; z[1] = zb1; z[2] = zb2; z[3] = zb3;
#pragma unroll
    for (int q = 4; q < NQ; ++q)
        z[q] = ((t >> (NQ - 1 - q)) & 1) ? -ptot : ptot;

    // wave (64-lane) shuffle reduction, then cross-wave via LDS
#pragma unroll
    for (int q = 0; q < NQ; ++q) {
#pragma unroll
        for (int off = 32; off > 0; off >>= 1)
            z[q] += __shfl_down(z[q], off, 64);
    }
    if (lane == 0) {
#pragma unroll
        for (int q = 0; q < NQ; ++q) red[wave * NQ + q] = z[q];
    }
    __syncthreads();
    if (t < NQ) {
        float r = red[t] + red[NQ + t] + red[2 * NQ + t] + red[3 * NQ + t];
        if (bf) ((__hip_bfloat16*)outp)[b * NQ + t] = __float2bfloat16(r);
        else    ((float*)outp)[b * NQ + t] = r;
    }
}

extern "C" void kernel_launch(void* const* d_in, const int* in_sizes, int n_in,
                              void* d_out, int out_size, void* d_ws, size_t ws_size,
                              hipStream_t stream) {
    const void* x     = d_in[0];
    const void* theta = d_in[1];
    const void* lam   = d_in[2];
    const int B = in_sizes[0] / NQ;  // 1024
    vqc_kernel<<<B, TPB, 0, stream>>>(x, theta, lam, d_out);
}

// Round 3
// 92.377 us; speedup vs baseline: 1.4352x; 1.4352x over previous
//
#include <hip/hip_runtime.h>
#include <hip/hip_bf16.h>
#include <math.h>

#define NQ 12
#define TPB 64

// One WAVE per sample (64-thread blocks, B=1024 blocks -> 4 waves/CU, all
// resident). Full 4096-amp state in registers: v[64] float2 per lane.
//   Layout L : amp j = r*64 + lane   (r bits = j bits 6..11 -> qubits 5..0)
//   Layout L': amp j = lane*64 + r   (r bits = j bits 0..5  -> qubits 11..6)
// Gates on register-resident qubits are pure VALU with compile-time pair
// indices. Commuting gates within a pass are reordered: 6 gates in one
// layout, LDS transpose (XOR-swizzled), 6 in the other. CNOT rings: layer-0
// folded into init via inverse permutation; layer-1 is one LDS scatter that
// also performs the L->L' layout change. Total LDS: 4 roundtrips (512 b64).

__device__ __forceinline__ float ldin(const void* p, int i, bool bf) {
    return bf ? __bfloat162float(((const __hip_bfloat16*)p)[i])
              : ((const float*)p)[i];
}

__device__ __forceinline__ void g_fused(float2& a0, float2& a1,
    float g00x, float g00y, float g01x, float g01y,
    float g10x, float g10y, float g11x, float g11y)
{
    float n0x = g00x*a0.x - g00y*a0.y + g01x*a1.x - g01y*a1.y;
    float n0y = g00x*a0.y + g00y*a0.x + g01x*a1.y + g01y*a1.x;
    float n1x = g10x*a0.x - g10y*a0.y + g11x*a1.x - g11y*a1.y;
    float n1y = g10x*a0.y + g10y*a0.x + g11x*a1.y + g11y*a1.x;
    a0.x = n0x; a0.y = n0y; a1.x = n1x; a1.y = n1y;
}

__device__ __forceinline__ void g_rx(float2& a0, float2& a1, float c, float s)
{
    float n0x = c*a0.x + s*a1.y;
    float n0y = c*a0.y - s*a1.x;
    float n1x = c*a1.x + s*a0.y;
    float n1y = c*a1.y - s*a0.x;
    a0.x = n0x; a0.y = n0y; a1.x = n1x; a1.y = n1y;
}

__device__ __forceinline__ void g_ry(float2& a0, float2& a1, float c, float s)
{
    float n0x = c*a0.x - s*a1.x;
    float n0y = c*a0.y - s*a1.y;
    float n1x = s*a0.x + c*a1.x;
    float n1y = s*a0.y + c*a1.y;
    a0.x = n0x; a0.y = n0y; a1.x = n1x; a1.y = n1y;
}

#define FOR_PAIRS(RB, STMT) do {                                  \
    const int msk_ = 1 << (RB);                                   \
    _Pragma("unroll")                                             \
    for (int h_ = 0; h_ < 32; ++h_) {                             \
        const int i0 = ((h_ & ~(msk_ - 1)) << 1) | (h_ & (msk_ - 1)); \
        const int i1 = i0 | msk_;                                 \
        STMT;                                                     \
    } } while (0)

__global__ __launch_bounds__(TPB, 1) void vqc_kernel(
    const void* __restrict__ xp,    // [B, 12]
    const void* __restrict__ thp,   // [2, 12, 2]
    const void* __restrict__ lmp,   // [2, 12]
    void* __restrict__ outp)        // [B, 12]
{
    __shared__ float2 S[4096];
    const int b = blockIdx.x;
    const int l = threadIdx.x;      // lane 0..63

    const bool bf = (*(const unsigned int*)lmp) == 0x3F803F80u;

    float2 v[64];

    // ---- layer-0 RX angles ----
    float c0[NQ], s0[NQ];
#pragma unroll
    for (int q = 0; q < NQ; ++q) {
        float h = 0.5f * ldin(lmp, q, bf) * ldin(xp, b * NQ + q, bf);
        __sincosf(h, &s0[q], &c0[q]);
    }

    // ---- init in L, layer-0 ring folded via inverse perm ----
    // inv perm: i_p = j_p^j_{p+1} (p<=9), i_10 = j_10^j_0^j_11, i_11 = j_0^j_11
    const int gl = (l ^ (l >> 1)) & 31;          // i bits 0..4 (qubits 11..7)
    float Plo = 1.0f;
#pragma unroll
    for (int p = 0; p < 5; ++p)
        Plo *= ((gl >> p) & 1) ? s0[11 - p] : c0[11 - p];
    const int plo_cnt = __popc(gl);
    const int l0 = l & 1, l5 = (l >> 5) & 1;

#pragma unroll
    for (int r = 0; r < 64; ++r) {
        const int r0 = r & 1, r1 = (r >> 1) & 1, r2 = (r >> 2) & 1,
                  r3 = (r >> 3) & 1, r4 = (r >> 4) & 1, r5 = (r >> 5) & 1;
        const int q5b = r0 ^ r1, q4b = r1 ^ r2, q3b = r2 ^ r3, q2b = r3 ^ r4;
        int b5  = l5 ^ r0;             // qubit 6
        int b10 = l0 ^ (r4 ^ r5);      // qubit 1
        int b11 = l0 ^ r5;             // qubit 0
        float m = Plo;
        m *= q5b ? s0[5] : c0[5];      // compile-time selects
        m *= q4b ? s0[4] : c0[4];
        m *= q3b ? s0[3] : c0[3];
        m *= q2b ? s0[2] : c0[2];
        m *= b5  ? s0[6] : c0[6];
        m *= b10 ? s0[1] : c0[1];
        m *= b11 ? s0[0] : c0[0];
        int k = (plo_cnt + b5 + b10 + b11 + (q5b + q4b + q3b + q2b)) & 3;
        v[r].x = (k == 0) ? m : ((k == 2) ? -m : 0.0f);
        v[r].y = (k == 3) ? m : ((k == 1) ? -m : 0.0f);
    }

    // ---- layer-0 fused RZ*RY, qubits 0..5 (L: rb = 5-q) ----
#pragma unroll
    for (int q = 0; q < 6; ++q) {
        float hy = 0.5f * ldin(thp, q * 2 + 0, bf);
        float hz = 0.5f * ldin(thp, q * 2 + 1, bf);
        float cy, sy, cz, sz;
        __sincosf(hy, &sy, &cy);
        __sincosf(hz, &sz, &cz);
        float g00x =  cz * cy, g00y = -sz * cy;
        float g01x = -cz * sy, g01y =  sz * sy;
        float g10x =  cz * sy, g10y =  sz * sy;
        float g11x =  cz * cy, g11y =  sz * cy;
        FOR_PAIRS(5 - q, g_fused(v[i0], v[i1], g00x, g00y, g01x, g01y,
                                 g10x, g10y, g11x, g11y));
    }

    // ---- transpose L -> L' (XOR swizzle: phys(j) = (j>>6)*64 + ((j&63)^(j>>6))) ----
#pragma unroll
    for (int r = 0; r < 64; ++r) S[r * 64 + (l ^ r)] = v[r];
    __syncthreads();
#pragma unroll
    for (int r = 0; r < 64; ++r) v[r] = S[l * 64 + (r ^ l)];
    __syncthreads();

    // ---- layer-0 fused RZ*RY, qubits 6..11 (L': rb = 11-q) ----
#pragma unroll
    for (int q = 6; q < 12; ++q) {
        float hy = 0.5f * ldin(thp, q * 2 + 0, bf);
        float hz = 0.5f * ldin(thp, q * 2 + 1, bf);
        float cy, sy, cz, sz;
        __sincosf(hy, &sy, &cy);
        __sincosf(hz, &sz, &cz);
        float g00x =  cz * cy, g00y = -sz * cy;
        float g01x = -cz * sy, g01y =  sz * sy;
        float g10x =  cz * sy, g10y =  sz * sy;
        float g11x =  cz * cy, g11y =  sz * cy;
        FOR_PAIRS(11 - q, g_fused(v[i0], v[i1], g00x, g00y, g01x, g01y,
                                  g10x, g10y, g11x, g11y));
    }

    // ---- layer-1 RX, qubits 6..11 (still L') ----
#pragma unroll
    for (int q = 6; q < 12; ++q) {
        float h = 0.5f * ldin(lmp, NQ + q, bf) * ldin(xp, b * NQ + q, bf);
        float c, s;
        __sincosf(h, &s, &c);
        FOR_PAIRS(11 - q, g_rx(v[i0], v[i1], c, s));
    }

    // ---- transpose L' -> L ----
#pragma unroll
    for (int r = 0; r < 64; ++r) S[l * 64 + (r ^ l)] = v[r];
    __syncthreads();
#pragma unroll
    for (int r = 0; r < 64; ++r) v[r] = S[r * 64 + (l ^ r)];
    __syncthreads();

    // ---- layer-1 RX, qubits 0..5 (L) ----
#pragma unroll
    for (int q = 0; q < 6; ++q) {
        float h = 0.5f * ldin(lmp, NQ + q, bf) * ldin(xp, b * NQ + q, bf);
        float c, s;
        __sincosf(h, &s, &c);
        FOR_PAIRS(5 - q, g_rx(v[i0], v[i1], c, s));
    }

    // ---- layer-1 ring: scatter perm(i), land in L' ----
    // sp = suffix-xor(i) low 11 bits | parity(bits 0..10 of i) << 11
    {
        int sl6 = (l ^ (l >> 1)); sl6 ^= sl6 >> 2; sl6 ^= sl6 >> 4; // 6-bit suffix-xor
        const int plp = __popc(l) & 1;
#pragma unroll
        for (int r = 0; r < 64; ++r) {
            const int Pr = __popc((unsigned)r) & 1;     // parity(r) -> folds
            const int Mr = Pr ? 63 : 0;
            int yr = (r ^ (r >> 1)); yr ^= yr >> 2; yr ^= yr >> 4;  // folds
            const int Yh = yr & 31;
            const int Cr = (__popc((unsigned)r) + ((r >> 5) & 1)) & 1;
            int sp_lo = sl6 ^ Mr;
            int sp_hi = Yh | (((plp ^ Cr) & 1) << 5);
            S[sp_hi * 64 + (sp_lo ^ sp_hi)] = v[r];     // swizzled write
        }
        __syncthreads();
#pragma unroll
        for (int r = 0; r < 64; ++r) v[r] = S[l * 64 + (r ^ l)];  // read in L'
        __syncthreads();
    }

    // ---- layer-1 RY, qubits 6..11 (L'); final RZ dropped (phase-only) ----
#pragma unroll
    for (int q = 6; q < 12; ++q) {
        float hy = 0.5f * ldin(thp, 24 + q * 2 + 0, bf);
        float cy, sy;
        __sincosf(hy, &sy, &cy);
        FOR_PAIRS(11 - q, g_ry(v[i0], v[i1], cy, sy));
    }

    // ---- transpose L' -> L ----
#pragma unroll
    for (int r = 0; r < 64; ++r) S[l * 64 + (r ^ l)] = v[r];
    __syncthreads();
#pragma unroll
    for (int r = 0; r < 64; ++r) v[r] = S[r * 64 + (l ^ r)];
    __syncthreads();

    // ---- layer-1 RY, qubits 0..5 (L) ----
#pragma unroll
    for (int q = 0; q < 6; ++q) {
        float hy = 0.5f * ldin(thp, 24 + q * 2 + 0, bf);
        float cy, sy;
        __sincosf(hy, &sy, &cy);
        FOR_PAIRS(5 - q, g_ry(v[i0], v[i1], cy, sy));
    }

    // ---- measurement in L ----
    float ptot = 0.0f;
    float zb[6] = {0, 0, 0, 0, 0, 0};
#pragma unroll
    for (int r = 0; r < 64; ++r) {
        float p = v[r].x * v[r].x + v[r].y * v[r].y;
        ptot += p;
#pragma unroll
        for (int q = 0; q < 6; ++q)
            zb[q] += ((r >> (5 - q)) & 1) ? -p : p;   // compile-time add/sub
    }
    float t[12];
#pragma unroll
    for (int q = 0; q < 6; ++q) t[q] = zb[q];
#pragma unroll
    for (int j = 0; j < 6; ++j)
        t[6 + j] = ((l >> (5 - j)) & 1) ? -ptot : ptot;
#pragma unroll
    for (int q = 0; q < 12; ++q) {
#pragma unroll
        for (int m = 1; m < 64; m <<= 1)
            t[q] += __shfl_xor(t[q], m, 64);
    }

    if (l == 0) {
        if (bf) {
#pragma unroll
            for (int q = 0; q < NQ; ++q)
                ((__hip_bfloat16*)outp)[b * NQ + q] = __float2bfloat16(t[q]);
        } else {
            float4* o = (float4*)((float*)outp + b * NQ);  // 48B*b: 16B aligned
            o[0] = make_float4(t[0], t[1], t[2], t[3]);
            o[1] = make_float4(t[4], t[5], t[6], t[7]);
            o[2] = make_float4(t[8], t[9], t[10], t[11]);
        }
    }
}

extern "C" void kernel_launch(void* const* d_in, const int* in_sizes, int n_in,
                              void* d_out, int out_size, void* d_ws, size_t ws_size,
                              hipStream_t stream) {
    const int B = in_sizes[0] / NQ;  // 1024
    vqc_kernel<<<B, TPB, 0, stream>>>(d_in[0], d_in[1], d_in[2], d_out);
}